// Round 1
// baseline (348.636 us; speedup 1.0000x reference)
//
#include <hip/hip_runtime.h>

// VQ-VAE vector quantizer, fp32.
// z: [16,64,32,32], emb: [8192,64]. N=16384 points (b*1024+hw), C=64, V=8192.
// out = [ z_q_st (1048576 f32) | idx as f32 (16384) | vq_loss (1) ]
//
// K1 is a register-tiled fp32 "GEMM + running argmax":
//   score(n,v) = z_n . e_v - 0.5*||e_v||^2   (argmax score == argmin dist)
// block = 256 thr (tx 0..15, ty 0..15), tile 128 pts x 128 codes/chunk,
// 8x8 per-thread micro-tile, V split 4-ways over blockIdx.y -> grid 512
// = exactly 2 blocks/CU (balanced), LDS ~68KB/block (gfx950 has 160KB).

#define N_PTS   16384
#define S_SPLITS 4
#define MB_PTS  128
#define VB      128
#define CODES_PER_SPLIT (8192 / S_SPLITS)   // 2048
#define CHUNKS  (CODES_PER_SPLIT / VB)      // 16

// ---------------- K0: half-norms of codebook ----------------
__global__ __launch_bounds__(256) void k0_norms(const float* __restrict__ emb,
                                                float* __restrict__ h) {
  int v = blockIdx.x * 256 + threadIdx.x;   // grid 32 -> 8192
  const float4* e4 = (const float4*)(emb + v * 64);
  float s = 0.f;
#pragma unroll
  for (int i = 0; i < 16; ++i) {
    float4 q = e4[i];
    s += q.x * q.x + q.y * q.y + q.z * q.z + q.w * q.w;
  }
  h[v] = 0.5f * s;
}

// ---------------- K1: tiled score + per-split argmax ----------------
__global__ __launch_bounds__(256, 2) void k1_argmax(
    const float* __restrict__ z, const float* __restrict__ emb,
    const float* __restrict__ h,
    float* __restrict__ pscore, int* __restrict__ pidx) {
  __shared__ float z_t[64][128];   // [k][m]  transposed z tile, 32 KB
  __shared__ float e_s[128][68];   // [v][k]  straight copy, padded, 34 KB
  __shared__ float h_s[128];

  const int tid = threadIdx.x;
  const int tx = tid & 15;
  const int ty = tid >> 4;
  const int mb = blockIdx.x;       // 0..127 point-tiles
  const int split = blockIdx.y;    // 0..3

  const int n_base = mb * MB_PTS;
  const int b = n_base >> 10;
  const int hwb = n_base & 1023;

  // stage z tile once: z[b][c][hwb+m] -> z_t[c][m]; conflict-free b128 writes
  {
    const float* zb = z + b * 65536 + hwb;
#pragma unroll
    for (int q = 0; q < 8; ++q) {
      int f = q * 1024 + tid * 4;        // f = c*128 + m
      int c = f >> 7, m = f & 127;
      float4 val = *(const float4*)(zb + c * 1024 + m);
      *(float4*)&z_t[c][m] = val;
    }
  }

  float best_s[8];
  int best_i[8];
#pragma unroll
  for (int i = 0; i < 8; ++i) { best_s[i] = -3.0e38f; best_i[i] = 0; }

  const int v_split_base = split * CODES_PER_SPLIT;

  for (int ch = 0; ch < CHUNKS; ++ch) {
    const int vb = v_split_base + ch * VB;
    __syncthreads();   // previous chunk's e_s reads done
    {
      const float* eb = emb + vb * 64;
#pragma unroll
      for (int q = 0; q < 8; ++q) {
        int f = q * 1024 + tid * 4;      // f = v*64 + c
        int v = f >> 6, c = f & 63;
        float4 val = *(const float4*)(eb + f);
        *(float4*)&e_s[v][c] = val;
      }
      if (tid < 128) h_s[tid] = h[vb + tid];
    }
    __syncthreads();

    float hv[8];
#pragma unroll
    for (int j = 0; j < 8; ++j) hv[j] = h_s[tx + 16 * j];

    float acc[8][8];
#pragma unroll
    for (int i = 0; i < 8; ++i)
#pragma unroll
      for (int j = 0; j < 8; ++j) acc[i][j] = 0.f;

#pragma unroll 4
    for (int k4 = 0; k4 < 16; ++k4) {
      float4 ef[8];
#pragma unroll
      for (int j = 0; j < 8; ++j)
        ef[j] = *(const float4*)&e_s[tx + 16 * j][k4 * 4];
      float4 za[4][2];
#pragma unroll
      for (int kk = 0; kk < 4; ++kk) {
        za[kk][0] = *(const float4*)&z_t[k4 * 4 + kk][ty * 8];
        za[kk][1] = *(const float4*)&z_t[k4 * 4 + kk][ty * 8 + 4];
      }
#pragma unroll
      for (int kk = 0; kk < 4; ++kk)
#pragma unroll
        for (int i = 0; i < 8; ++i) {
          float zv = ((const float*)&za[kk][i >> 2])[i & 3];
#pragma unroll
          for (int j = 0; j < 8; ++j)
            acc[i][j] = fmaf(zv, ((const float*)&ef[j])[kk], acc[i][j]);
        }
    }

    // running argmax; v ascends with j -> strict > keeps first occurrence
#pragma unroll
    for (int j = 0; j < 8; ++j) {
      int vg = vb + tx + 16 * j;
#pragma unroll
      for (int i = 0; i < 8; ++i) {
        float sc = acc[i][j] - hv[j];
        if (sc > best_s[i]) { best_s[i] = sc; best_i[i] = vg; }
      }
    }
  }

  // butterfly argmax across the 16 tx lanes (tie -> lower index)
#pragma unroll
  for (int off = 8; off >= 1; off >>= 1) {
#pragma unroll
    for (int i = 0; i < 8; ++i) {
      float os = __shfl_xor(best_s[i], off);
      int oi = __shfl_xor(best_i[i], off);
      if (os > best_s[i] || (os == best_s[i] && oi < best_i[i])) {
        best_s[i] = os; best_i[i] = oi;
      }
    }
  }
  if (tx == 0) {
    int nb = n_base + ty * 8;
#pragma unroll
    for (int i = 0; i < 8; ++i) {
      pscore[split * N_PTS + nb + i] = best_s[i];
      pidx[split * N_PTS + nb + i] = best_i[i];
    }
  }
}

// ---------------- K2: reduce splits, emit idx ----------------
__global__ __launch_bounds__(256) void k2_reduce(
    const float* __restrict__ pscore, const int* __restrict__ pidx,
    int* __restrict__ idx_final, float* __restrict__ out_idx,
    float* __restrict__ acc) {
  int n = blockIdx.x * 256 + threadIdx.x;   // grid 64 -> 16384
  float bs = pscore[n];
  int bi = pidx[n];
#pragma unroll
  for (int s = 1; s < S_SPLITS; ++s) {
    float os = pscore[s * N_PTS + n];
    int oi = pidx[s * N_PTS + n];
    if (os > bs || (os == bs && oi < bi)) { bs = os; bi = oi; }
  }
  idx_final[n] = bi;
  out_idx[n] = (float)bi;
  if (n == 0) *acc = 0.f;
}

// ---------------- K3: gather, straight-through out, loss partial ----------------
__global__ __launch_bounds__(256) void k3_quant(
    const float* __restrict__ z, const float* __restrict__ emb,
    const int* __restrict__ idx_final,
    float* __restrict__ out, float* __restrict__ acc) {
  int g = blockIdx.x * 256 + threadIdx.x;   // grid 4096 -> 1048576, [b][c][hw]
  int b = g >> 16;
  int c = (g >> 10) & 63;
  int hw = g & 1023;
  int n = (b << 10) | hw;
  float zv = z[g];
  float q = emb[idx_final[n] * 64 + c];
  float d = q - zv;
  out[g] = zv + d;          // z + (z_q - z), matches reference fp order
  float val = d * d;
#pragma unroll
  for (int off = 32; off >= 1; off >>= 1) val += __shfl_down(val, off);
  __shared__ float wsum[4];
  int lane = threadIdx.x & 63, wv = threadIdx.x >> 6;
  if (lane == 0) wsum[wv] = val;
  __syncthreads();
  if (threadIdx.x == 0)
    atomicAdd(acc, wsum[0] + wsum[1] + wsum[2] + wsum[3]);
}

// ---------------- K4: finalize loss ----------------
__global__ void k4_loss(const float* __restrict__ acc, float* __restrict__ out_loss) {
  // codebook + beta*commit = (1 + 0.25) * mean((q - z)^2)
  out_loss[0] = 1.25f * acc[0] * (1.0f / 1048576.0f);
}

extern "C" void kernel_launch(void* const* d_in, const int* in_sizes, int n_in,
                              void* d_out, int out_size, void* d_ws, size_t ws_size,
                              hipStream_t stream) {
  const float* z   = (const float*)d_in[0];   // 16*64*32*32
  const float* emb = (const float*)d_in[1];   // 8192*64
  float* out = (float*)d_out;
  float* ws  = (float*)d_ws;

  // ws layout (floats): h[8192] | pscore[4*16384] | pidx[4*16384] | idxf[16384] | acc[1]
  float* h      = ws;
  float* pscore = ws + 8192;
  int*   pidx   = (int*)(ws + 8192 + 4 * N_PTS);
  int*   idxf   = (int*)(ws + 8192 + 8 * N_PTS);
  float* acc    = ws + 8192 + 9 * N_PTS;

  float* out_zq   = out;                       // 1048576
  float* out_idx  = out + 1048576;             // 16384
  float* out_loss = out + 1048576 + 16384;     // 1

  k0_norms<<<32, 256, 0, stream>>>(emb, h);
  k1_argmax<<<dim3(128, S_SPLITS), 256, 0, stream>>>(z, emb, h, pscore, pidx);
  k2_reduce<<<64, 256, 0, stream>>>(pscore, pidx, idxf, out_idx, acc);
  k3_quant<<<4096, 256, 0, stream>>>(z, emb, idxf, out, acc);
  k4_loss<<<1, 1, 0, stream>>>(acc, out_loss);
}